// Round 15
// baseline (76.163 us; speedup 1.0000x reference)
//
#include <hip/hip_runtime.h>

typedef unsigned int u32;
typedef _Float16 f16;
typedef f16 f16x2 __attribute__((ext_vector_type(2)));
typedef f16 f16x4 __attribute__((ext_vector_type(4)));
typedef f16 f16x8 __attribute__((ext_vector_type(8)));
typedef float f32x4 __attribute__((ext_vector_type(4)));

#define LSEQ 900
#define BATCH 4
#define NWIN (BATCH*LSEQ)
#define NBLK NWIN         // encoder: 1 window/block
#define MT 57             // attn m-tiles per batch
#define NABLK (BATCH*MT)  // 228
#define NHBLK (NWIN/8)    // 450 head_qkv blocks

__device__ __forceinline__ float eluf(float x){ return x > 0.f ? x : __expf(x) - 1.f; }
#define BC2(u) __builtin_bit_cast(f16x2, (u))
#define ZERO4H ((f16x4){(f16)0,(f16)0,(f16)0,(f16)0})
#define ZERO8H __builtin_bit_cast(f16x8, (uint4{0,0,0,0}))

// ---- LDS map (u32 words), encoder ----
#define P0U 0
#define P1U 2112
#define FEATU 3872
#define SMTOT 4080
#define T1F 0
#define H2F 4224
#define T2F 0
#define H3F 4224
#define T3F 0
#define FEATF 7744

// ---- ws f16 offsets ----
#define WB2A 0
#define WB2B 512
#define WB3  768
#define WB4  2304
#define WFC1 5376
#define WEND 58624
#define WPM  58624                  // PM : 576000
#define WPTE (WPM + 576000)
#define WPZ  (WPTE + 576000)
#define WQH  (WPZ + 576000)         // qh : 145920
#define WKH  (WQH + 145920)
#define WVT  (WKH + 145920)         // vT : 145920
#define WF32 ((WVT + 145920)/2)     // f32 word offset (even)
// f32: zt @WF32 (144000), h1 @WF32+144000 (460800)

#define PREP_BLOCKS ((WEND+255)/256)        // 229
#define CONV_BLOCKS ((144000+255)/256)      // 563

// ============ fused prep: weight packing + direct PM/PTE/PZ ============
__global__ __launch_bounds__(256) void prep_all(
    const float* __restrict__ z,
    const float* __restrict__ cw1, const float* __restrict__ cb1,
    const float* __restrict__ cw2, const float* __restrict__ cw3,
    const float* __restrict__ cw4, const float* __restrict__ fc1w,
    f16* __restrict__ wsF, f16* __restrict__ PM, f16* __restrict__ PTE, f16* __restrict__ PZ)
{
  const int blk = blockIdx.x;
  if (blk < PREP_BLOCKS) {
    const int g = blk*256 + threadIdx.x;
    if (g >= WEND) return;
    float val;
    if (g < 512) {
      const int l = g>>3, j = g&7;
      const int oc = l&15, c = l>>4;
      const int dr = c>>1, dc = 2*(c&1) + (j>>2), ic = j&3;
      val = (oc<8 && dc<3) ? cw2[oc*36 + ic*9 + dr*3 + dc] : 0.f;
    } else if (g < 768) {
      const int u = g-512, l = u>>2, j = u&3;
      const int oc = l&15, dc = l>>4, ic = j;
      val = (oc<8 && dc<3) ? cw2[oc*36 + ic*9 + 6 + dc] : 0.f;
    } else if (g < 2304) {
      const int u = g-768, dr = u>>9, r = u&511, l = r>>3, j = r&7;
      const int oc = l&15, dc = l>>4, ic = j;
      val = (dc<3) ? cw3[oc*72 + ic*9 + dr*3 + dc] : 0.f;
    } else if (g < 5376) {
      const int u = g-2304, v = u>>9, dr = v>>1, h = v&1;
      const int r = u&511, l = r>>3, j = r&7;
      const int oc = l&15, chunk = l>>4;
      const int dcl = chunk>>1, ic = (chunk&1)*8 + j, dc = h*2 + dcl;
      val = (dc<3) ? cw4[oc*144 + ic*9 + dr*3 + dc] : 0.f;
    } else {
      const int u = g - WFC1;
      const int j = u&7, l = (u>>3)&63, st = (u>>9)%13, nt = u/(13*512);
      const int k = st*32 + (l>>4)*8 + j, n = nt*16 + (l&15);
      val = (k<400) ? fc1w[n*400 + k] : 0.f;
    }
    wsF[g] = (f16)val;
  } else {
    const int g = (blk - PREP_BLOCKS)*256 + threadIdx.x;
    if (g >= 144000) return;
    const int cp = g % 40, fb2 = g / 40, f = fb2 % 900, b = fb2 / 900;
    if (f >= 899) return;
    const int c0 = 2*cp;
    const float* zb = z + b*72000;
    float p[4][4];
    #pragma unroll
    for (int dr = 0; dr < 4; ++dr) {
      const int r = f - 1 + dr;
      const bool rok = (r >= 0) && (r < 900);
      #pragma unroll
      for (int dc = 0; dc < 4; ++dc) {
        const int cc = c0 + dc - 1;
        p[dr][dc] = (rok && cc >= 0 && cc < 80) ? zb[r*80+cc] : 0.f;
      }
    }
    f16x4 opm, opte, opz;
    #pragma unroll
    for (int oc = 0; oc < 4; ++oc) {
      float pmv = -3.4e38f, ptev = -3.4e38f, pzv = -3.4e38f;
      #pragma unroll
      for (int col = 0; col < 2; ++col) {
        float te = cb1[oc];
        float s0 = 0.f;
        float c1n = cb1[oc];
        #pragma unroll
        for (int dc = 0; dc < 3; ++dc) {
          const float w0 = cw1[oc*9 + dc], w1 = cw1[oc*9 + 3 + dc], w2 = cw1[oc*9 + 6 + dc];
          s0  += w0 * p[0][col+dc];
          te  += w1 * p[1][col+dc] + w2 * p[2][col+dc];
          c1n += w0 * p[1][col+dc] + w1 * p[2][col+dc] + w2 * p[3][col+dc];
        }
        const float cf = te + s0;
        pmv  = fmaxf(pmv,  fmaxf(cf, c1n));
        ptev = fmaxf(ptev, fmaxf(te, c1n));
        pzv  = fmaxf(pzv,  fmaxf(te, 0.f));
      }
      opm[oc]  = (f16)eluf(pmv);
      opte[oc] = (f16)eluf(ptev);
      opz[oc]  = (f16)eluf(pzv);
    }
    *(f16x4*)(PM  + g*4) = opm;
    *(f16x4*)(PTE + g*4) = opte;
    *(f16x4*)(PZ  + g*4) = opz;
  }
}

// ============ encoder: stage1 row copy; stages 2-4 + fc1 MFMA; ends at h1 global store ============
__global__ __launch_bounds__(256,8) void encoder7(
    const f16* __restrict__ PM, const f16* __restrict__ PTE, const f16* __restrict__ PZ,
    const float* __restrict__ cb2, const float* __restrict__ cb3, const float* __restrict__ cb4,
    const f16* __restrict__ wsF, const float* __restrict__ fc1b,
    float* __restrict__ h1g)
{
  __shared__ __align__(16) u32 sm[SMTOT];
  f16* smh = (f16*)sm;
  const int tid = threadIdx.x, blk = blockIdx.x;
  const int lane = tid & 63, wid = tid >> 6;
  const int b = blk/LSEQ, i0 = blk%LSEQ;

  // ---- stage1: indexed row gather, f16x8 ----
  {
    const int e45 = min(i0 + 23, LSEQ) - 45;
    const int sv  = max(i0 - 22, 0);
    const f16* PMb  = PM  + b*144000;
    const f16* PTEb = PTE + b*144000;
    const f16* PZb  = PZ  + b*144000;
    for (int s = tid; s < 440; s += 256) {
      const int pr = s/20, pcp = s%20;
      const int fa = e45 + 2*pr;
      f16x8 v = ZERO8H;
      if (fa > sv)         v = *(const f16x8*)(PMb  + (fa*40 + 2*pcp)*4);
      else if (fa == sv)   v = *(const f16x8*)(PTEb + (fa*40 + 2*pcp)*4);
      else if (fa == sv-1) v = *(const f16x8*)(PZb  + (sv*40 + 2*pcp)*4);
      f16* dst = smh + T1F + ((pr+1)*44 + 2*pcp+1)*4;
      *(f16x4*)(dst)     = __builtin_shufflevector(v, v, 0,1,2,3);
      *(f16x4*)(dst + 4) = __builtin_shufflevector(v, v, 4,5,6,7);
    }
    for (int s = tid; s < 176; s += 256) {
      int r, c;
      if (s < 44)      { r = 0;  c = s; }
      else if (s < 88) { r = 23; c = s-44; }
      else {
        const int t = s - 88;
        const int which = t / 22;
        r = (t % 22) + 1;
        c = which == 0 ? 0 : (which == 1 ? 41 : (which == 2 ? 42 : 43));
      }
      *(f16x4*)(smh + T1F + (r*44+c)*4) = ZERO4H;
    }
    if (tid < 2) ((uint4*)(sm))[FEATU/4 + 50 + tid] = (uint4){0,0,0,0};
  }
  __syncthreads();

  // ---- stage2 MFMA ----
  {
    const f16x8 B2a = *(const f16x8*)(wsF + WB2A + lane*8);
    const f16x4 B2b = *(const f16x4*)(wsF + WB2B + lane*4);
    const int oc = lane&15, chunk = lane>>4;
    const float bias2 = (oc<8) ? cb2[oc] : 0.f;
    int r2 = (wid*16 + oc)/40, c2 = (wid*16 + oc)%40;
    int rE = (wid*16 + chunk*4)/40, cE = (wid*16 + chunk*4)%40;
    for (int t = wid; t < 55; t += 4) {
      const f16* base = smh + T1F;
      const f16* pA = base + ((r2 + (chunk>>1))*44 + c2 + 2*(chunk&1))*4;
      const f16x4 lo = *(const f16x4*)(pA);
      const f16x4 hi = *(const f16x4*)(pA + 4);
      const f16x8 a8 = __builtin_shufflevector(lo, hi, 0,1,2,3,4,5,6,7);
      f32x4 acc = {bias2, bias2, bias2, bias2};
      acc = __builtin_amdgcn_mfma_f32_16x16x32_f16(a8, B2a, acc, 0, 0, 0);
      const f16x4 a4 = *(const f16x4*)(base + ((r2+2)*44 + c2 + chunk)*4);
      acc = __builtin_amdgcn_mfma_f32_16x16x16f16(a4, B2b, acc, 0, 0, 0);
      if (oc < 8) {
        f16* h2o = smh + H2F;
        h2o[(rE*20 + (cE>>1))*8 + oc] = (f16)fmaxf(acc[0], acc[1]);
        const int cE2 = cE + 2;
        const int rE2 = rE + (cE2 >= 40 ? 1 : 0);
        const int cE3 = cE2 >= 40 ? cE2 - 40 : cE2;
        h2o[(rE2*20 + (cE3>>1))*8 + oc] = (f16)fmaxf(acc[2], acc[3]);
      }
      { const int cn = c2 + 24; const int cy = cn >= 40;
        r2 += 1 + cy; c2 = cy ? cn - 40 : cn; }
      { const int cn = cE + 24; const int cy = cn >= 40;
        rE += 1 + cy; cE = cy ? cn - 40 : cn; }
    }
  }
  __syncthreads();

  // ---- vmax+elu H2 -> T2 ----
  {
    for (int s = tid; s < 312; s += 256) {
      const int r = s/24, c = s%24;
      if (!(r>=1 && r<=11 && c>=1 && c<=20)) {
        const uint4 z4 = {0,0,0,0};
        *(uint4*)(smh + T2F + (r*24+c)*8) = z4;
      }
    }
    for (int s = tid; s < 880; s += 256) {
      const int pr = s/80, rem = s%80, cp = rem/4, op = rem%4;
      const u32* h2 = (const u32*)(smh + H2F);
      const u32 a  = h2[((2*pr  )*20 + cp)*4 + op];
      const u32 b2 = h2[((2*pr+1)*20 + cp)*4 + op];
      const f16x2 av = BC2(a), bv = BC2(b2);
      f16x2 o;
      o.x = (f16)eluf(fmaxf((float)av.x, (float)bv.x));
      o.y = (f16)eluf(fmaxf((float)av.y, (float)bv.y));
      ((u32*)(smh + T2F))[((pr+1)*24 + cp+1)*4 + op] = __builtin_bit_cast(u32, o);
    }
  }
  __syncthreads();

  // ---- stage3 MFMA ----
  {
    f16x8 B3r[3];
    #pragma unroll
    for (int dr = 0; dr < 3; ++dr) B3r[dr] = *(const f16x8*)(wsF + WB3 + dr*512 + lane*8);
    const int oc = lane&15, chunk = lane>>4;
    const float bias3 = cb3[oc];
    for (int t = wid; t < 14; t += 4) {
      const int mA = t*16 + oc;
      const int r3 = mA/20, c3 = mA%20;
      const f16* base = smh + T2F;
      f32x4 acc = {bias3, bias3, bias3, bias3};
      #pragma unroll
      for (int dr = 0; dr < 3; ++dr) {
        const f16x8 a8 = *(const f16x8*)(base + ((r3+dr)*24 + c3 + chunk)*8);
        acc = __builtin_amdgcn_mfma_f32_16x16x32_f16(a8, B3r[dr], acc, 0, 0, 0);
      }
      #pragma unroll
      for (int p = 0; p < 2; ++p) {
        const int mE = t*16 + chunk*4 + 2*p;
        if (mE < 220) {
          const int rE = mE/20, cE = mE%20;
          if (rE < 10)
            smh[H3F + (rE*10 + (cE>>1))*16 + oc] = (f16)fmaxf(acc[2*p], acc[2*p+1]);
        }
      }
    }
  }
  __syncthreads();

  // ---- vmax+elu H3 -> T3 ----
  {
    for (int s = tid; s < 98; s += 256) {
      const int r = s/14, c = s%14;
      if (!(r>=1 && r<=5 && c>=1 && c<=10)) {
        const uint4 z4 = {0,0,0,0};
        *(uint4*)(smh + T3F + (r*14+c)*16)     = z4;
        *(uint4*)(smh + T3F + (r*14+c)*16 + 8) = z4;
      }
    }
    for (int s = tid; s < 400; s += 256) {
      const int pr = s/80, rem = s%80, cp = rem/8, op = rem%8;
      const u32* h3 = (const u32*)(smh + H3F);
      const u32 a  = h3[((2*pr  )*10 + cp)*8 + op];
      const u32 b2 = h3[((2*pr+1)*10 + cp)*8 + op];
      const f16x2 av = BC2(a), bv = BC2(b2);
      f16x2 o;
      o.x = (f16)eluf(fmaxf((float)av.x, (float)bv.x));
      o.y = (f16)eluf(fmaxf((float)av.y, (float)bv.y));
      ((u32*)(smh + T3F))[((pr+1)*14 + cp+1)*8 + op] = __builtin_bit_cast(u32, o);
    }
  }
  __syncthreads();

  // ---- stage4 MFMA -> feat ----
  {
    f16x8 B4r[6];
    #pragma unroll
    for (int v = 0; v < 6; ++v) B4r[v] = *(const f16x8*)(wsF + WB4 + v*512 + lane*8);
    const int oc = lane&15, chunk = lane>>4;
    const int dcl = chunk>>1, hsel = chunk&1;
    const float bias4 = cb4[oc];
    for (int t = wid; t < 4; t += 4) {
      const int mA = t*16 + oc;
      const int mmA = mA < 50 ? mA : mA - 50;
      const int r4 = mmA/10, c4 = mmA%10;
      const f16* base = smh + T3F;
      f32x4 acc = {bias4, bias4, bias4, bias4};
      #pragma unroll
      for (int v = 0; v < 6; ++v) {
        const int dr = v>>1, h = v&1;
        const f16x8 a8 = *(const f16x8*)(base + ((r4+dr)*14 + c4 + h*2 + dcl)*16 + hsel*8);
        acc = __builtin_amdgcn_mfma_f32_16x16x32_f16(a8, B4r[v], acc, 0, 0, 0);
      }
      #pragma unroll
      for (int p = 0; p < 2; ++p) {
        const int mE = t*16 + chunk*4 + 2*p;
        if (mE < 50) {
          const int rE = mE/10, cE = mE%10;
          smh[FEATF + oc*25 + rE*5 + (cE>>1)] = (f16)eluf(fmaxf(acc[2*p], acc[2*p+1]));
        }
      }
    }
  }
  __syncthreads();

  // ---- fc1 MFMA -> h1 global (elu), no trailing barrier ----
  {
    float* dst = h1g + (b*LSEQ + i0)*128;
    #pragma unroll
    for (int q2 = 0; q2 < 2; ++q2) {
      const int nt = wid + q2*4;
      f32x4 acc = {0.f, 0.f, 0.f, 0.f};
      for (int st = 0; st < 13; ++st) {
        const f16x8 a8 = *(const f16x8*)(smh + FEATF + st*32 + (lane>>4)*8);
        const f16x8 b8 = *(const f16x8*)(wsF + WFC1 + ((nt*13 + st)*64 + lane)*8);
        acc = __builtin_amdgcn_mfma_f32_16x16x32_f16(a8, b8, acc, 0, 0, 0);
      }
      if (lane < 16) {
        const int n = nt*16 + lane;
        dst[n] = eluf(acc[0] + fc1b[n]);
      }
    }
  }
}

// ============ head_qkv: fc2 -> emb -> qkv for 8 rows/block, fully parallel ============
__global__ __launch_bounds__(256) void head_qkv(
    const float* __restrict__ h1g, const float* __restrict__ toh,
    const float* __restrict__ fc2w, const float* __restrict__ fc2b,
    const float* __restrict__ embw, const float* __restrict__ embb,
    const float* __restrict__ wq, const float* __restrict__ bq,
    const float* __restrict__ wk, const float* __restrict__ bk,
    const float* __restrict__ wv, const float* __restrict__ bv,
    float* __restrict__ zt_g, f16* __restrict__ qh,
    f16* __restrict__ kh, f16* __restrict__ vT)
{
  __shared__ __align__(16) float h1s[8][128];
  __shared__ __align__(16) float zps[8][40];
  __shared__ __align__(16) float zts[8][40];
  const int tid = threadIdx.x, blk = blockIdx.x;
  const int r0 = blk*8;

  {
    const int r = tid >> 5, c = tid & 31;
    ((float4*)h1s[r])[c] = ((const float4*)(h1g + (r0+r)*128))[c];
  }
  __syncthreads();

  for (int s = tid; s < 320; s += 256) {
    const int r = s/40, n = s%40;
    const float4* hv = (const float4*)h1s[r];
    const float4* wr = (const float4*)(fc2w + n*128);
    float acc = fc2b[n];
    #pragma unroll 8
    for (int c = 0; c < 32; ++c) {
      const float4 a = wr[c], x = hv[c];
      acc += a.x*x.x + a.y*x.y + a.z*x.z + a.w*x.w;
    }
    zps[r][n] = acc;
  }
  __syncthreads();

  for (int s = tid; s < 320; s += 256) {
    const int r = s/40, n = s%40;
    const int row = r0 + r, b = row/LSEQ;
    const float* wr = embw + n*45;
    float acc = embb[n];
    #pragma unroll 8
    for (int j = 0; j < 40; ++j) acc += wr[j]*zps[r][j];
    #pragma unroll
    for (int j = 0; j < 5; ++j)  acc += wr[40+j]*toh[b*5 + j];
    const float v = eluf(acc);
    zts[r][n] = v;
    zt_g[row*40 + n] = v;
  }
  __syncthreads();

  for (int s = tid; s < 960; s += 256) {
    const int which = s/320, u = s%320, r = u/40, n = u%40;
    const int row = r0 + r, b = row/LSEQ, i = row%LSEQ;
    const float* wm = which==0 ? wq : (which==1 ? wk : wv);
    const float* bb = which==0 ? bq : (which==1 ? bk : bv);
    const float4* wr = (const float4*)(wm + n*40);
    const float4* zv = (const float4*)zts[r];
    float acc = bb[n];
    #pragma unroll
    for (int c = 0; c < 10; ++c) {
      const float4 a = wr[c], x = zv[c];
      acc += a.x*x.x + a.y*x.y + a.z*x.z + a.w*x.w;
    }
    if (which == 0)      qh[b*36480 + i*40 + n] = (f16)acc;
    else if (which == 1) kh[b*36480 + i*40 + n] = (f16)acc;
    else                 vT[b*36480 + n*912 + i] = (f16)acc;
  }
}

// ============ attn7: MFMA attention, 512 threads ============
__global__ __launch_bounds__(512) void attn7(
    const f16* __restrict__ qh, const f16* __restrict__ kh,
    const f16* __restrict__ vT, const float* __restrict__ zt_g,
    const int* __restrict__ dur,
    const float* __restrict__ flw1, const float* __restrict__ flb1,
    const float* __restrict__ flw2, const float* __restrict__ flb2,
    const float* __restrict__ stw1, const float* __restrict__ stb1,
    const float* __restrict__ stw2, const float* __restrict__ stb2,
    const float* __restrict__ edw1, const float* __restrict__ edb1,
    const float* __restrict__ edw2, const float* __restrict__ edb2,
    float* __restrict__ out)
{
  __shared__ __align__(16) f16 P[16*916];
  __shared__ float denp[8][16];
  __shared__ float pvp[8][16][48];
  __shared__ __align__(16) float xr[16][40];
  __shared__ float hb[16][30];

  const int tid = threadIdx.x;
  const int w = tid >> 6, l = tid & 63;
  const int col = l & 15, kg = l >> 4;
  const int blk = blockIdx.x;
  const int b = blk / MT, mt = blk % MT;
  const int m0 = mt * 16;
  const int durb = dur[b];
  const float scale = 0.15811388300841897f;

  const f16* qb = qh + b*36480;
  const f16* kb = kh + b*36480;
  const f16* vb = vT + b*36480;

  f16x4 aq[3];
  #pragma unroll
  for (int kst = 0; kst < 3; ++kst) {
    const int k0 = kst*16 + kg*4;
    aq[kst] = (k0 < 40) ? *(const f16x4*)(qb + (m0 + col)*40 + k0) : ZERO4H;
  }

  float sum4[4] = {0.f, 0.f, 0.f, 0.f};
  for (int nt = w; nt < 57; nt += 8) {
    const int n = nt*16 + col;
    f32x4 acc = {0.f, 0.f, 0.f, 0.f};
    #pragma unroll
    for (int kst = 0; kst < 3; ++kst) {
      const int k0 = kst*16 + kg*4;
      const f16x4 bfrag = (k0 < 40) ? *(const f16x4*)(kb + n*40 + k0) : ZERO4H;
      acc = __builtin_amdgcn_mfma_f32_16x16x16f16(aq[kst], bfrag, acc, 0, 0, 0);
    }
    #pragma unroll
    for (int i = 0; i < 4; ++i) {
      const int mrow = kg*4 + i;
      const int mg = m0 + mrow;
      float p;
      if (n >= 900)                    p = 0.f;
      else if (mg >= durb || n >= durb) p = 1.f;
      else                              p = __expf(acc[i]*scale);
      P[mrow*916 + n] = (f16)p;
      sum4[i] += p;
    }
  }
  #pragma unroll
  for (int i = 0; i < 4; ++i) {
    #pragma unroll
    for (int off = 1; off < 16; off <<= 1) sum4[i] += __shfl_xor(sum4[i], off);
  }
  if (col == 0) {
    #pragma unroll
    for (int i = 0; i < 4; ++i) denp[w][kg*4 + i] = sum4[i];
  }
  __syncthreads();

  {
    f32x4 acc3[3] = {{0.f,0.f,0.f,0.f},{0.f,0.f,0.f,0.f},{0.f,0.f,0.f,0.f}};
    for (int kt = w; kt < 57; kt += 8) {
      const f16x4 ap = *(const f16x4*)(P + col*916 + kt*16 + kg*4);
      #pragma unroll
      for (int nt = 0; nt < 3; ++nt) {
        const int n = nt*16 + col;
        const f16x4 bv = (n < 40) ? *(const f16x4*)(vb + n*912 + kt*16 + kg*4) : ZERO4H;
        acc3[nt] = __builtin_amdgcn_mfma_f32_16x16x16f16(ap, bv, acc3[nt], 0, 0, 0);
      }
    }
    #pragma unroll
    for (int nt = 0; nt < 3; ++nt)
      #pragma unroll
      for (int i = 0; i < 4; ++i)
        pvp[w][kg*4 + i][nt*16 + col] = acc3[nt][i];
  }
  __syncthreads();

  for (int s = tid; s < 640; s += 512) {
    const int m = s/40, d = s%40;
    float den = 0.f, pv = 0.f;
    #pragma unroll
    for (int ww = 0; ww < 8; ++ww) { den += denp[ww][m]; pv += pvp[ww][m][d]; }
    const int mg = min(m0 + m, 899);
    xr[m][d] = pv/den + zt_g[(b*LSEQ + mg)*40 + d];
  }
  __syncthreads();

  if (tid < 480) {
    const int m = tid/30, rr = tid%30, hd = rr/10, j = rr%10;
    const float* w1 = hd==0?flw1:(hd==1?stw1:edw1);
    const float* b1 = hd==0?flb1:(hd==1?stb1:edb1);
    float a = b1[j];
    #pragma unroll 8
    for (int d = 0; d < 40; ++d) a += w1[j*40+d]*xr[m][d];
    hb[m][hd*10+j] = eluf(a);
  }
  __syncthreads();
  if (tid < 48) {
    const int m = tid/3, hd = tid%3;
    if (m0 + m < 900) {
      const float* w2 = hd==0?flw2:(hd==1?stw2:edw2);
      const float* b2 = hd==0?flb2:(hd==1?stb2:edb2);
      float a = b2[0];
      #pragma unroll
      for (int j = 0; j < 10; ++j) a += w2[j]*hb[m][hd*10+j];
      out[hd*NWIN + b*LSEQ + m0 + m] = a;
    }
  }
}

extern "C" void kernel_launch(void* const* d_in, const int* in_sizes, int n_in,
                              void* d_out, int out_size, void* d_ws, size_t ws_size,
                              hipStream_t stream) {
  const float* z    = (const float*)d_in[0];
  const float* toh  = (const float*)d_in[1];
  const int*   dur  = (const int*)d_in[2];
  const float* cw1  = (const float*)d_in[3];
  const float* cb1  = (const float*)d_in[4];
  const float* cw2  = (const float*)d_in[5];
  const float* cb2  = (const float*)d_in[6];
  const float* cw3  = (const float*)d_in[7];
  const float* cb3  = (const float*)d_in[8];
  const float* cw4  = (const float*)d_in[9];
  const float* cb4  = (const float*)d_in[10];
  const float* fc1w = (const float*)d_in[11];
  const float* fc1b = (const float*)d_in[12];
  const float* fc2w = (const float*)d_in[13];
  const float* fc2b = (const float*)d_in[14];
  const float* embw = (const float*)d_in[15];
  const float* embb = (const float*)d_in[16];
  const float* wq   = (const float*)d_in[17];
  const float* bq   = (const float*)d_in[18];
  const float* wk   = (const float*)d_in[19];
  const float* bk   = (const float*)d_in[20];
  const float* wv   = (const float*)d_in[21];
  const float* bv   = (const float*)d_in[22];
  const float* flw1 = (const float*)d_in[23];
  const float* flb1 = (const float*)d_in[24];
  const float* flw2 = (const float*)d_in[25];
  const float* flb2 = (const float*)d_in[26];
  const float* stw1 = (const float*)d_in[27];
  const float* stb1 = (const float*)d_in[28];
  const float* stw2 = (const float*)d_in[29];
  const float* stb2 = (const float*)d_in[30];
  const float* edw1 = (const float*)d_in[31];
  const float* edb1 = (const float*)d_in[32];
  const float* edw2 = (const float*)d_in[33];
  const float* edb2 = (const float*)d_in[34];

  f16*   wsF = (f16*)d_ws;
  f16*   PM  = wsF + WPM;
  f16*   PTE = wsF + WPTE;
  f16*   PZ  = wsF + WPZ;
  f16*   qh  = wsF + WQH;
  f16*   kh  = wsF + WKH;
  f16*   vT  = wsF + WVT;
  float* zt  = (float*)d_ws + WF32;
  float* h1g = (float*)d_ws + WF32 + 144000;

  prep_all<<<PREP_BLOCKS + CONV_BLOCKS, 256, 0, stream>>>(z, cw1, cb1, cw2, cw3, cw4, fc1w,
                                                          wsF, PM, PTE, PZ);
  encoder7<<<NBLK, 256, 0, stream>>>(PM, PTE, PZ, cb2, cb3, cb4, wsF, fc1b, h1g);
  head_qkv<<<NHBLK, 256, 0, stream>>>(h1g, toh, fc2w, fc2b, embw, embb,
                                      wq, bq, wk, bk, wv, bv, zt, qh, kh, vT);
  attn7<<<NABLK, 512, 0, stream>>>(qh, kh, vT, zt, dur,
                                   flw1, flb1, flw2, flb2,
                                   stw1, stb1, stw2, stb2,
                                   edw1, edb1, edw2, edb2,
                                   (float*)d_out);
}

// Round 16
// 68.866 us; speedup vs baseline: 1.1060x; 1.1060x over previous
//
#include <hip/hip_runtime.h>

typedef unsigned int u32;
typedef _Float16 f16;
typedef f16 f16x2 __attribute__((ext_vector_type(2)));
typedef f16 f16x4 __attribute__((ext_vector_type(4)));
typedef f16 f16x8 __attribute__((ext_vector_type(8)));
typedef float f32x4 __attribute__((ext_vector_type(4)));

#define LSEQ 900
#define BATCH 4
#define NWIN (BATCH*LSEQ)
#define NBLK NWIN         // encoder: 1 window/block
#define MT 57             // attn m-tiles per batch
#define NABLK (BATCH*MT)  // 228

__device__ __forceinline__ float eluf(float x){ return x > 0.f ? x : __expf(x) - 1.f; }
#define BC2(u) __builtin_bit_cast(f16x2, (u))
#define ZERO4H ((f16x4){(f16)0,(f16)0,(f16)0,(f16)0})
#define ZERO8H __builtin_bit_cast(f16x8, (uint4{0,0,0,0}))

// ---- LDS map (u32 words), encoder ----
#define P0U 0
#define P1U 2112
#define FEATU 3872
#define F32U 4080
#define SMTOT 4288
#define T1F 0
#define H2F 4224
#define T2F 0
#define H3F 4224
#define T3F 0
#define FEATF 7744

// ---- ws f16 offsets ----
#define WB2A 0
#define WB2B 512
#define WB3  768
#define WB4  2304
#define WFC1 5376
#define WEND 58624
#define WPM  58624                  // PM : 576000
#define WPTE (WPM + 576000)
#define WPZ  (WPTE + 576000)
#define WQH  (WPZ + 576000)         // qh : 145920
#define WKH  (WQH + 145920)
#define WVT  (WKH + 145920)         // vT : 145920
#define WF32 ((WVT + 145920)/2)     // f32 word offset (even)
// f32: zt @WF32 (144000)

#define PREP_BLOCKS ((WEND+255)/256)        // 229
#define CONV_BLOCKS ((144000+255)/256)      // 563

// ============ fused prep: weight packing + direct PM/PTE/PZ ============
__global__ __launch_bounds__(256) void prep_all(
    const float* __restrict__ z,
    const float* __restrict__ cw1, const float* __restrict__ cb1,
    const float* __restrict__ cw2, const float* __restrict__ cw3,
    const float* __restrict__ cw4, const float* __restrict__ fc1w,
    f16* __restrict__ wsF, f16* __restrict__ PM, f16* __restrict__ PTE, f16* __restrict__ PZ)
{
  const int blk = blockIdx.x;
  if (blk < PREP_BLOCKS) {
    const int g = blk*256 + threadIdx.x;
    if (g >= WEND) return;
    float val;
    if (g < 512) {
      const int l = g>>3, j = g&7;
      const int oc = l&15, c = l>>4;
      const int dr = c>>1, dc = 2*(c&1) + (j>>2), ic = j&3;
      val = (oc<8 && dc<3) ? cw2[oc*36 + ic*9 + dr*3 + dc] : 0.f;
    } else if (g < 768) {
      const int u = g-512, l = u>>2, j = u&3;
      const int oc = l&15, dc = l>>4, ic = j;
      val = (oc<8 && dc<3) ? cw2[oc*36 + ic*9 + 6 + dc] : 0.f;
    } else if (g < 2304) {
      const int u = g-768, dr = u>>9, r = u&511, l = r>>3, j = r&7;
      const int oc = l&15, dc = l>>4, ic = j;
      val = (dc<3) ? cw3[oc*72 + ic*9 + dr*3 + dc] : 0.f;
    } else if (g < 5376) {
      const int u = g-2304, v = u>>9, dr = v>>1, h = v&1;
      const int r = u&511, l = r>>3, j = r&7;
      const int oc = l&15, chunk = l>>4;
      const int dcl = chunk>>1, ic = (chunk&1)*8 + j, dc = h*2 + dcl;
      val = (dc<3) ? cw4[oc*144 + ic*9 + dr*3 + dc] : 0.f;
    } else {
      const int u = g - WFC1;
      const int j = u&7, l = (u>>3)&63, st = (u>>9)%13, nt = u/(13*512);
      const int k = st*32 + (l>>4)*8 + j, n = nt*16 + (l&15);
      val = (k<400) ? fc1w[n*400 + k] : 0.f;
    }
    wsF[g] = (f16)val;
  } else {
    const int g = (blk - PREP_BLOCKS)*256 + threadIdx.x;
    if (g >= 144000) return;
    const int cp = g % 40, fb2 = g / 40, f = fb2 % 900, b = fb2 / 900;
    if (f >= 899) return;
    const int c0 = 2*cp;
    const float* zb = z + b*72000;
    float p[4][4];
    #pragma unroll
    for (int dr = 0; dr < 4; ++dr) {
      const int r = f - 1 + dr;
      const bool rok = (r >= 0) && (r < 900);
      #pragma unroll
      for (int dc = 0; dc < 4; ++dc) {
        const int cc = c0 + dc - 1;
        p[dr][dc] = (rok && cc >= 0 && cc < 80) ? zb[r*80+cc] : 0.f;
      }
    }
    f16x4 opm, opte, opz;
    #pragma unroll
    for (int oc = 0; oc < 4; ++oc) {
      float pmv = -3.4e38f, ptev = -3.4e38f, pzv = -3.4e38f;
      #pragma unroll
      for (int col = 0; col < 2; ++col) {
        float te = cb1[oc];
        float s0 = 0.f;
        float c1n = cb1[oc];
        #pragma unroll
        for (int dc = 0; dc < 3; ++dc) {
          const float w0 = cw1[oc*9 + dc], w1 = cw1[oc*9 + 3 + dc], w2 = cw1[oc*9 + 6 + dc];
          s0  += w0 * p[0][col+dc];
          te  += w1 * p[1][col+dc] + w2 * p[2][col+dc];
          c1n += w0 * p[1][col+dc] + w1 * p[2][col+dc] + w2 * p[3][col+dc];
        }
        const float cf = te + s0;
        pmv  = fmaxf(pmv,  fmaxf(cf, c1n));
        ptev = fmaxf(ptev, fmaxf(te, c1n));
        pzv  = fmaxf(pzv,  fmaxf(te, 0.f));
      }
      opm[oc]  = (f16)eluf(pmv);
      opte[oc] = (f16)eluf(ptev);
      opz[oc]  = (f16)eluf(pzv);
    }
    *(f16x4*)(PM  + g*4) = opm;
    *(f16x4*)(PTE + g*4) = opte;
    *(f16x4*)(PZ  + g*4) = opz;
  }
}

// ============ encoder: stage1 row copy; stages 2-4 + fc1 MFMA; all-thread epilogue ============
__global__ __launch_bounds__(256,8) void encoder8(
    const f16* __restrict__ PM, const f16* __restrict__ PTE, const f16* __restrict__ PZ,
    const float* __restrict__ toh,
    const float* __restrict__ cb2, const float* __restrict__ cb3, const float* __restrict__ cb4,
    const f16* __restrict__ wsF,
    const float* __restrict__ fc1b, const float* __restrict__ fc2w, const float* __restrict__ fc2b,
    const float* __restrict__ embw, const float* __restrict__ embb,
    const float* __restrict__ wq, const float* __restrict__ bq,
    const float* __restrict__ wk, const float* __restrict__ bk,
    const float* __restrict__ wv, const float* __restrict__ bv,
    float* __restrict__ zt_g, f16* __restrict__ qh,
    f16* __restrict__ kh, f16* __restrict__ vT)
{
  __shared__ __align__(16) u32 sm[SMTOT];
  f16* smh = (f16*)sm;
  const int tid = threadIdx.x, blk = blockIdx.x;
  const int lane = tid & 63, wid = tid >> 6;
  const int b = blk/LSEQ, i0 = blk%LSEQ;

  // ---- stage1: indexed row gather, f16x8 ----
  {
    const int e45 = min(i0 + 23, LSEQ) - 45;
    const int sv  = max(i0 - 22, 0);
    const f16* PMb  = PM  + b*144000;
    const f16* PTEb = PTE + b*144000;
    const f16* PZb  = PZ  + b*144000;
    for (int s = tid; s < 440; s += 256) {
      const int pr = s/20, pcp = s%20;
      const int fa = e45 + 2*pr;
      f16x8 v = ZERO8H;
      if (fa > sv)         v = *(const f16x8*)(PMb  + (fa*40 + 2*pcp)*4);
      else if (fa == sv)   v = *(const f16x8*)(PTEb + (fa*40 + 2*pcp)*4);
      else if (fa == sv-1) v = *(const f16x8*)(PZb  + (sv*40 + 2*pcp)*4);
      f16* dst = smh + T1F + ((pr+1)*44 + 2*pcp+1)*4;
      *(f16x4*)(dst)     = __builtin_shufflevector(v, v, 0,1,2,3);
      *(f16x4*)(dst + 4) = __builtin_shufflevector(v, v, 4,5,6,7);
    }
    for (int s = tid; s < 176; s += 256) {
      int r, c;
      if (s < 44)      { r = 0;  c = s; }
      else if (s < 88) { r = 23; c = s-44; }
      else {
        const int t = s - 88;
        const int which = t / 22;
        r = (t % 22) + 1;
        c = which == 0 ? 0 : (which == 1 ? 41 : (which == 2 ? 42 : 43));
      }
      *(f16x4*)(smh + T1F + (r*44+c)*4) = ZERO4H;
    }
    if (tid < 2) ((uint4*)(sm))[FEATU/4 + 50 + tid] = (uint4){0,0,0,0};
  }
  __syncthreads();

  // ---- stage2 MFMA ----
  {
    const f16x8 B2a = *(const f16x8*)(wsF + WB2A + lane*8);
    const f16x4 B2b = *(const f16x4*)(wsF + WB2B + lane*4);
    const int oc = lane&15, chunk = lane>>4;
    const float bias2 = (oc<8) ? cb2[oc] : 0.f;
    int r2 = (wid*16 + oc)/40, c2 = (wid*16 + oc)%40;
    int rE = (wid*16 + chunk*4)/40, cE = (wid*16 + chunk*4)%40;
    for (int t = wid; t < 55; t += 4) {
      const f16* base = smh + T1F;
      const f16* pA = base + ((r2 + (chunk>>1))*44 + c2 + 2*(chunk&1))*4;
      const f16x4 lo = *(const f16x4*)(pA);
      const f16x4 hi = *(const f16x4*)(pA + 4);
      const f16x8 a8 = __builtin_shufflevector(lo, hi, 0,1,2,3,4,5,6,7);
      f32x4 acc = {bias2, bias2, bias2, bias2};
      acc = __builtin_amdgcn_mfma_f32_16x16x32_f16(a8, B2a, acc, 0, 0, 0);
      const f16x4 a4 = *(const f16x4*)(base + ((r2+2)*44 + c2 + chunk)*4);
      acc = __builtin_amdgcn_mfma_f32_16x16x16f16(a4, B2b, acc, 0, 0, 0);
      if (oc < 8) {
        f16* h2o = smh + H2F;
        h2o[(rE*20 + (cE>>1))*8 + oc] = (f16)fmaxf(acc[0], acc[1]);
        const int cE2 = cE + 2;
        const int rE2 = rE + (cE2 >= 40 ? 1 : 0);
        const int cE3 = cE2 >= 40 ? cE2 - 40 : cE2;
        h2o[(rE2*20 + (cE3>>1))*8 + oc] = (f16)fmaxf(acc[2], acc[3]);
      }
      { const int cn = c2 + 24; const int cy = cn >= 40;
        r2 += 1 + cy; c2 = cy ? cn - 40 : cn; }
      { const int cn = cE + 24; const int cy = cn >= 40;
        rE += 1 + cy; cE = cy ? cn - 40 : cn; }
    }
  }
  __syncthreads();

  // ---- vmax+elu H2 -> T2 ----
  {
    for (int s = tid; s < 312; s += 256) {
      const int r = s/24, c = s%24;
      if (!(r>=1 && r<=11 && c>=1 && c<=20)) {
        const uint4 z4 = {0,0,0,0};
        *(uint4*)(smh + T2F + (r*24+c)*8) = z4;
      }
    }
    for (int s = tid; s < 880; s += 256) {
      const int pr = s/80, rem = s%80, cp = rem/4, op = rem%4;
      const u32* h2 = (const u32*)(smh + H2F);
      const u32 a  = h2[((2*pr  )*20 + cp)*4 + op];
      const u32 b2 = h2[((2*pr+1)*20 + cp)*4 + op];
      const f16x2 av = BC2(a), bv = BC2(b2);
      f16x2 o;
      o.x = (f16)eluf(fmaxf((float)av.x, (float)bv.x));
      o.y = (f16)eluf(fmaxf((float)av.y, (float)bv.y));
      ((u32*)(smh + T2F))[((pr+1)*24 + cp+1)*4 + op] = __builtin_bit_cast(u32, o);
    }
  }
  __syncthreads();

  // ---- stage3 MFMA ----
  {
    f16x8 B3r[3];
    #pragma unroll
    for (int dr = 0; dr < 3; ++dr) B3r[dr] = *(const f16x8*)(wsF + WB3 + dr*512 + lane*8);
    const int oc = lane&15, chunk = lane>>4;
    const float bias3 = cb3[oc];
    for (int t = wid; t < 14; t += 4) {
      const int mA = t*16 + oc;
      const int r3 = mA/20, c3 = mA%20;
      const f16* base = smh + T2F;
      f32x4 acc = {bias3, bias3, bias3, bias3};
      #pragma unroll
      for (int dr = 0; dr < 3; ++dr) {
        const f16x8 a8 = *(const f16x8*)(base + ((r3+dr)*24 + c3 + chunk)*8);
        acc = __builtin_amdgcn_mfma_f32_16x16x32_f16(a8, B3r[dr], acc, 0, 0, 0);
      }
      #pragma unroll
      for (int p = 0; p < 2; ++p) {
        const int mE = t*16 + chunk*4 + 2*p;
        if (mE < 220) {
          const int rE = mE/20, cE = mE%20;
          if (rE < 10)
            smh[H3F + (rE*10 + (cE>>1))*16 + oc] = (f16)fmaxf(acc[2*p], acc[2*p+1]);
        }
      }
    }
  }
  __syncthreads();

  // ---- vmax+elu H3 -> T3 ----
  {
    for (int s = tid; s < 98; s += 256) {
      const int r = s/14, c = s%14;
      if (!(r>=1 && r<=5 && c>=1 && c<=10)) {
        const uint4 z4 = {0,0,0,0};
        *(uint4*)(smh + T3F + (r*14+c)*16)     = z4;
        *(uint4*)(smh + T3F + (r*14+c)*16 + 8) = z4;
      }
    }
    for (int s = tid; s < 400; s += 256) {
      const int pr = s/80, rem = s%80, cp = rem/8, op = rem%8;
      const u32* h3 = (const u32*)(smh + H3F);
      const u32 a  = h3[((2*pr  )*10 + cp)*8 + op];
      const u32 b2 = h3[((2*pr+1)*10 + cp)*8 + op];
      const f16x2 av = BC2(a), bv = BC2(b2);
      f16x2 o;
      o.x = (f16)eluf(fmaxf((float)av.x, (float)bv.x));
      o.y = (f16)eluf(fmaxf((float)av.y, (float)bv.y));
      ((u32*)(smh + T3F))[((pr+1)*14 + cp+1)*8 + op] = __builtin_bit_cast(u32, o);
    }
  }
  __syncthreads();

  // ---- stage4 MFMA -> feat ----
  {
    f16x8 B4r[6];
    #pragma unroll
    for (int v = 0; v < 6; ++v) B4r[v] = *(const f16x8*)(wsF + WB4 + v*512 + lane*8);
    const int oc = lane&15, chunk = lane>>4;
    const int dcl = chunk>>1, hsel = chunk&1;
    const float bias4 = cb4[oc];
    for (int t = wid; t < 4; t += 4) {
      const int mA = t*16 + oc;
      const int mmA = mA < 50 ? mA : mA - 50;
      const int r4 = mmA/10, c4 = mmA%10;
      const f16* base = smh + T3F;
      f32x4 acc = {bias4, bias4, bias4, bias4};
      #pragma unroll
      for (int v = 0; v < 6; ++v) {
        const int dr = v>>1, h = v&1;
        const f16x8 a8 = *(const f16x8*)(base + ((r4+dr)*14 + c4 + h*2 + dcl)*16 + hsel*8);
        acc = __builtin_amdgcn_mfma_f32_16x16x32_f16(a8, B4r[v], acc, 0, 0, 0);
      }
      #pragma unroll
      for (int p = 0; p < 2; ++p) {
        const int mE = t*16 + chunk*4 + 2*p;
        if (mE < 50) {
          const int rE = mE/10, cE = mE%10;
          smh[FEATF + oc*25 + rE*5 + (cE>>1)] = (f16)eluf(fmaxf(acc[2*p], acc[2*p+1]));
        }
      }
    }
  }
  __syncthreads();

  // ---- fc1 MFMA -> h1 LDS ----
  {
    float* h1 = (float*)(sm + F32U);
    #pragma unroll
    for (int q2 = 0; q2 < 2; ++q2) {
      const int nt = wid + q2*4;
      f32x4 acc = {0.f, 0.f, 0.f, 0.f};
      for (int st = 0; st < 13; ++st) {
        const f16x8 a8 = *(const f16x8*)(smh + FEATF + st*32 + (lane>>4)*8);
        const f16x8 b8 = *(const f16x8*)(wsF + WFC1 + ((nt*13 + st)*64 + lane)*8);
        acc = __builtin_amdgcn_mfma_f32_16x16x32_f16(a8, b8, acc, 0, 0, 0);
      }
      if (lane < 16) {
        const int n = nt*16 + lane;
        h1[n] = eluf(acc[0] + fc1b[n]);
      }
    }
  }
  __syncthreads();

  // ---- epilogue, all-thread parallel: fc2(160 thr, 4-way) -> emb(40 thr) -> qkv(240 thr, 2-way) ----
  float* h1f = (float*)(sm + F32U);
  float* zpf = h1f + 128;
  float* ztf = h1f + 168;
  if (tid < 160) {
    const int n = tid >> 2, seg = tid & 3;
    const float4* hv = (const float4*)h1f + seg*8;
    const float4* wr = (const float4*)(fc2w + n*128) + seg*8;
    float acc = 0.f;
    #pragma unroll
    for (int c = 0; c < 8; ++c) {
      const float4 a = wr[c], x = hv[c];
      acc += a.x*x.x + a.y*x.y + a.z*x.z + a.w*x.w;
    }
    acc += __shfl_xor(acc, 1);
    acc += __shfl_xor(acc, 2);
    if (seg == 0) zpf[n] = acc + fc2b[n];
  }
  __syncthreads();
  if (tid < 40) {
    const float* wr = embw + tid*45;
    float acc = embb[tid];
    #pragma unroll 8
    for (int j = 0; j < 40; ++j) acc += wr[j]*zpf[j];
    #pragma unroll
    for (int j = 0; j < 5; ++j)  acc += wr[40+j]*toh[b*5 + j];
    const float v2 = eluf(acc);
    ztf[tid] = v2;
    zt_g[(b*LSEQ + i0)*40 + tid] = v2;
  }
  __syncthreads();
  if (tid < 240) {
    const int o = tid >> 1, half = tid & 1;
    const int which = o / 40, n = o % 40;
    const float* wm = which==0 ? wq : (which==1 ? wk : wv);
    const float4* wr = (const float4*)(wm + n*40) + half*5;
    const float4* zv = (const float4*)ztf + half*5;
    float acc = 0.f;
    #pragma unroll
    for (int c = 0; c < 5; ++c) {
      const float4 a = wr[c], x = zv[c];
      acc += a.x*x.x + a.y*x.y + a.z*x.z + a.w*x.w;
    }
    acc += __shfl_xor(acc, 1);
    if (half == 0) {
      const float* bb = which==0 ? bq : (which==1 ? bk : bv);
      const float v2 = acc + bb[n];
      if (which == 0)      qh[b*36480 + i0*40 + n] = (f16)v2;
      else if (which == 1) kh[b*36480 + i0*40 + n] = (f16)v2;
      else                 vT[b*36480 + n*912 + i0] = (f16)v2;
    }
  }
}

// ============ attn7: MFMA attention, 512 threads ============
__global__ __launch_bounds__(512) void attn7(
    const f16* __restrict__ qh, const f16* __restrict__ kh,
    const f16* __restrict__ vT, const float* __restrict__ zt_g,
    const int* __restrict__ dur,
    const float* __restrict__ flw1, const float* __restrict__ flb1,
    const float* __restrict__ flw2, const float* __restrict__ flb2,
    const float* __restrict__ stw1, const float* __restrict__ stb1,
    const float* __restrict__ stw2, const float* __restrict__ stb2,
    const float* __restrict__ edw1, const float* __restrict__ edb1,
    const float* __restrict__ edw2, const float* __restrict__ edb2,
    float* __restrict__ out)
{
  __shared__ __align__(16) f16 P[16*916];
  __shared__ float denp[8][16];
  __shared__ float pvp[8][16][48];
  __shared__ __align__(16) float xr[16][40];
  __shared__ float hb[16][30];

  const int tid = threadIdx.x;
  const int w = tid >> 6, l = tid & 63;
  const int col = l & 15, kg = l >> 4;
  const int blk = blockIdx.x;
  const int b = blk / MT, mt = blk % MT;
  const int m0 = mt * 16;
  const int durb = dur[b];
  const float scale = 0.15811388300841897f;

  const f16* qb = qh + b*36480;
  const f16* kb = kh + b*36480;
  const f16* vb = vT + b*36480;

  f16x4 aq[3];
  #pragma unroll
  for (int kst = 0; kst < 3; ++kst) {
    const int k0 = kst*16 + kg*4;
    aq[kst] = (k0 < 40) ? *(const f16x4*)(qb + (m0 + col)*40 + k0) : ZERO4H;
  }

  float sum4[4] = {0.f, 0.f, 0.f, 0.f};
  for (int nt = w; nt < 57; nt += 8) {
    const int n = nt*16 + col;
    f32x4 acc = {0.f, 0.f, 0.f, 0.f};
    #pragma unroll
    for (int kst = 0; kst < 3; ++kst) {
      const int k0 = kst*16 + kg*4;
      const f16x4 bfrag = (k0 < 40) ? *(const f16x4*)(kb + n*40 + k0) : ZERO4H;
      acc = __builtin_amdgcn_mfma_f32_16x16x16f16(aq[kst], bfrag, acc, 0, 0, 0);
    }
    #pragma unroll
    for (int i = 0; i < 4; ++i) {
      const int mrow = kg*4 + i;
      const int mg = m0 + mrow;
      float p;
      if (n >= 900)                    p = 0.f;
      else if (mg >= durb || n >= durb) p = 1.f;
      else                              p = __expf(acc[i]*scale);
      P[mrow*916 + n] = (f16)p;
      sum4[i] += p;
    }
  }
  #pragma unroll
  for (int i = 0; i < 4; ++i) {
    #pragma unroll
    for (int off = 1; off < 16; off <<= 1) sum4[i] += __shfl_xor(sum4[i], off);
  }
  if (col == 0) {
    #pragma unroll
    for (int i = 0; i < 4; ++i) denp[w][kg*4 + i] = sum4[i];
  }
  __syncthreads();

  {
    f32x4 acc3[3] = {{0.f,0.f,0.f,0.f},{0.f,0.f,0.f,0.f},{0.f,0.f,0.f,0.f}};
    for (int kt = w; kt < 57; kt += 8) {
      const f16x4 ap = *(const f16x4*)(P + col*916 + kt*16 + kg*4);
      #pragma unroll
      for (int nt = 0; nt < 3; ++nt) {
        const int n = nt*16 + col;
        const f16x4 bv = (n < 40) ? *(const f16x4*)(vb + n*912 + kt*16 + kg*4) : ZERO4H;
        acc3[nt] = __builtin_amdgcn_mfma_f32_16x16x16f16(ap, bv, acc3[nt], 0, 0, 0);
      }
    }
    #pragma unroll
    for (int nt = 0; nt < 3; ++nt)
      #pragma unroll
      for (int i = 0; i < 4; ++i)
        pvp[w][kg*4 + i][nt*16 + col] = acc3[nt][i];
  }
  __syncthreads();

  for (int s = tid; s < 640; s += 512) {
    const int m = s/40, d = s%40;
    float den = 0.f, pv = 0.f;
    #pragma unroll
    for (int ww = 0; ww < 8; ++ww) { den += denp[ww][m]; pv += pvp[ww][m][d]; }
    const int mg = min(m0 + m, 899);
    xr[m][d] = pv/den + zt_g[(b*LSEQ + mg)*40 + d];
  }
  __syncthreads();

  if (tid < 480) {
    const int m = tid/30, rr = tid%30, hd = rr/10, j = rr%10;
    const float* w1 = hd==0?flw1:(hd==1?stw1:edw1);
    const float* b1 = hd==0?flb1:(hd==1?stb1:edb1);
    float a = b1[j];
    #pragma unroll 8
    for (int d = 0; d < 40; ++d) a += w1[j*40+d]*xr[m][d];
    hb[m][hd*10+j] = eluf(a);
  }
  __syncthreads();
  if (tid < 48) {
    const int m = tid/3, hd = tid%3;
    if (m0 + m < 900) {
      const float* w2 = hd==0?flw2:(hd==1?stw2:edw2);
      const float* b2 = hd==0?flb2:(hd==1?stb2:edb2);
      float a = b2[0];
      #pragma unroll
      for (int j = 0; j < 10; ++j) a += w2[j]*hb[m][hd*10+j];
      out[hd*NWIN + b*LSEQ + m0 + m] = a;
    }
  }
}

extern "C" void kernel_launch(void* const* d_in, const int* in_sizes, int n_in,
                              void* d_out, int out_size, void* d_ws, size_t ws_size,
                              hipStream_t stream) {
  const float* z    = (const float*)d_in[0];
  const float* toh  = (const float*)d_in[1];
  const int*   dur  = (const int*)d_in[2];
  const float* cw1  = (const float*)d_in[3];
  const float* cb1  = (const float*)d_in[4];
  const float* cw2  = (const float*)d_in[5];
  const float* cb2  = (const float*)d_in[6];
  const float* cw3  = (const float*)d_in[7];
  const float* cb3  = (const float*)d_in[8];
  const float* cw4  = (const float*)d_in[9];
  const float* cb4  = (const float*)d_in[10];
  const float* fc1w = (const float*)d_in[11];
  const float* fc1b = (const float*)d_in[12];
  const float* fc2w = (const float*)d_in[13];
  const float* fc2b = (const float*)d_in[14];
  const float* embw = (const float*)d_in[15];
  const float* embb = (const float*)d_in[16];
  const float* wq   = (const float*)d_in[17];
  const float* bq   = (const float*)d_in[18];
  const float* wk   = (const float*)d_in[19];
  const float* bk   = (const float*)d_in[20];
  const float* wv   = (const float*)d_in[21];
  const float* bv   = (const float*)d_in[22];
  const float* flw1 = (const float*)d_in[23];
  const float* flb1 = (const float*)d_in[24];
  const float* flw2 = (const float*)d_in[25];
  const float* flb2 = (const float*)d_in[26];
  const float* stw1 = (const float*)d_in[27];
  const float* stb1 = (const float*)d_in[28];
  const float* stw2 = (const float*)d_in[29];
  const float* stb2 = (const float*)d_in[30];
  const float* edw1 = (const float*)d_in[31];
  const float* edb1 = (const float*)d_in[32];
  const float* edw2 = (const float*)d_in[33];
  const float* edb2 = (const float*)d_in[34];

  f16*   wsF = (f16*)d_ws;
  f16*   PM  = wsF + WPM;
  f16*   PTE = wsF + WPTE;
  f16*   PZ  = wsF + WPZ;
  f16*   qh  = wsF + WQH;
  f16*   kh  = wsF + WKH;
  f16*   vT  = wsF + WVT;
  float* zt  = (float*)d_ws + WF32;

  prep_all<<<PREP_BLOCKS + CONV_BLOCKS, 256, 0, stream>>>(z, cw1, cb1, cw2, cw3, cw4, fc1w,
                                                          wsF, PM, PTE, PZ);
  encoder8<<<NBLK, 256, 0, stream>>>(PM, PTE, PZ, toh, cb2, cb3, cb4, wsF,
                                     fc1b, fc2w, fc2b, embw, embb,
                                     wq, bq, wk, bk, wv, bv, zt, qh, kh, vT);
  attn7<<<NABLK, 512, 0, stream>>>(qh, kh, vT, zt, dur,
                                   flw1, flb1, flw2, flb2,
                                   stw1, stb1, stw2, stb2,
                                   edw1, edb1, edw2, edb2,
                                   (float*)d_out);
}